// Round 1
// baseline (85.667 us; speedup 1.0000x reference)
//
#include <hip/hip_runtime.h>
#include <hip/hip_bf16.h>

typedef __attribute__((ext_vector_type(8))) short s16x8;
typedef __attribute__((ext_vector_type(4))) float f32x4;

constexpr int NB = 8, CI = 256, OC = 256, HH = 64, WW = 64, HP = 66, WP = 66;
constexpr int NBASES = 5;
constexpr int WELEMS = OC * CI * 9;      // 589824 per basis
constexpr int BM = 128, BN = 128, BK = 32;

static __device__ __forceinline__ unsigned short f2bf(float f) {
    unsigned int u = __builtin_bit_cast(unsigned int, f);
    unsigned int r = (u + 0x7fffu + ((u >> 16) & 1u)) >> 16;   // RNE
    return (unsigned short)r;
}

// ---- 1) per-basis partial sums of |w| : grid 5*64, block 256 ----
__global__ void k_abs_partial(const float* __restrict__ w, float* __restrict__ part) {
    int b = blockIdx.x >> 6, chunk = blockIdx.x & 63;
    const float4* v = (const float4*)(w + (size_t)b * WELEMS + (size_t)chunk * (WELEMS / 64));
    float s = 0.f;
    for (int i = threadIdx.x; i < WELEMS / 64 / 4; i += 256) {
        float4 t = v[i];
        s += fabsf(t.x) + fabsf(t.y) + fabsf(t.z) + fabsf(t.w);
    }
    #pragma unroll
    for (int off = 32; off; off >>= 1) s += __shfl_down(s, off, 64);
    __shared__ float ls[4];
    int lane = threadIdx.x & 63, wid = threadIdx.x >> 6;
    if (lane == 0) ls[wid] = s;
    __syncthreads();
    if (threadIdx.x == 0) part[blockIdx.x] = ls[0] + ls[1] + ls[2] + ls[3];
}

// ---- 2) finalize the 5 scales : grid 1, block 320 (5 waves) ----
__global__ void k_scales(const float* __restrict__ part, float* __restrict__ s) {
    int lane = threadIdx.x & 63, wid = threadIdx.x >> 6;
    float v = part[wid * 64 + lane];
    #pragma unroll
    for (int off = 32; off; off >>= 1) v += __shfl_down(v, off, 64);
    if (lane == 0) s[wid] = v * (1.0f / (float)WELEMS);
}

// ---- 3) wsum[tap][o][i] = (1/5) * sum_b sign(w[b,o,i,tap])*s_b, bf16 ----
// grid OC, block 256 (i)
__global__ void k_wsum(const float* __restrict__ w, const float* __restrict__ s,
                       unsigned short* __restrict__ wsum) {
    int o = blockIdx.x, i = threadIdx.x;
    float sc[NBASES];
    #pragma unroll
    for (int b = 0; b < NBASES; ++b) sc[b] = s[b];
    const float* base = w + ((size_t)(o * CI + i)) * 9;
    float acc[9];
    #pragma unroll
    for (int t = 0; t < 9; ++t) acc[t] = 0.f;
    #pragma unroll
    for (int b = 0; b < NBASES; ++b) {
        const float* wb = base + (size_t)b * WELEMS;
        #pragma unroll
        for (int t = 0; t < 9; ++t) {
            float xv = wb[t];
            acc[t] += (xv > 0.f) ? sc[b] : ((xv < 0.f) ? -sc[b] : 0.f);
        }
    }
    #pragma unroll
    for (int t = 0; t < 9; ++t)
        wsum[(t * OC + o) * CI + i] = f2bf(acc[t] * 0.2f);
}

// ---- 4) xq_pad[n][h+1][w+1][c] = bf16(round(clip(x[n][c][h][w],0,1))), borders 0 ----
// grid NB*HH (one (n,h) row per block), block 256
__global__ void k_quant(const float* __restrict__ x, unsigned short* __restrict__ xq) {
    __shared__ unsigned short tile[64][257];
    int nh = blockIdx.x, n = nh >> 6, h = nh & 63;
    const float* xb = x + ((size_t)n * CI) * (HH * WW) + h * WW;   // + c*4096 + w
    int tw = threadIdx.x & 63, tc0 = threadIdx.x >> 6;
    for (int c = tc0; c < CI; c += 4) {
        float v = xb[(size_t)c * (HH * WW) + tw];
        v = rintf(fminf(fmaxf(v, 0.f), 1.f));
        tile[tw][c] = f2bf(v);
    }
    __syncthreads();
    unsigned short* ob = xq + ((size_t)(n * HP + (h + 1)) * WP + 1) * CI;
    for (int wri = 0; wri < 64; ++wri)
        ob[wri * CI + threadIdx.x] = tile[wri][threadIdx.x];
    // zero the two side border cells of this padded row (w_p = 0 and 65)
    (ob - CI)[threadIdx.x] = 0;
    (ob + 64 * CI)[threadIdx.x] = 0;
    // blocks at h==0 / h==63 zero the full top/bottom padded rows of this n
    if (h == 0) {
        unsigned short* r0 = xq + ((size_t)(n * HP + 0) * WP) * CI;
        for (int i = threadIdx.x; i < WP * CI; i += 256) r0[i] = 0;
    }
    if (h == HH - 1) {
        unsigned short* r65 = xq + ((size_t)(n * HP + (HP - 1)) * WP) * CI;
        for (int i = threadIdx.x; i < WP * CI; i += 256) r65[i] = 0;
    }
}

// ---- 5) implicit-GEMM conv: 128 pixels x 128 oc, BK=32, 4 waves, bf16 MFMA ----
__launch_bounds__(256, 2)
__global__ void k_conv(const unsigned short* __restrict__ xq,
                       const unsigned short* __restrict__ wsum,
                       float* __restrict__ out) {
    __shared__ __align__(16) unsigned short lA[BM * BK];  // 8 KB
    __shared__ __align__(16) unsigned short lB[BN * BK];  // 8 KB

    int bx = blockIdx.x;
    int pt = bx >> 1, ot = bx & 1;
    int pb = pt * BM;                  // first pixel (n*4096 + h*64 + w)
    int n = pb >> 12;
    int h0 = (pb >> 6) & 63;           // even; rows 0..63 -> h0, 64..127 -> h0+1
    int oc0 = ot * BN;
    int tid = threadIdx.x;

    // staging: chunk q in [0,512): row=q>>2, s'=q&3, fetch global slot = s'^((row>>1)&3)
    int aOff[2], bOff[2];
    #pragma unroll
    for (int k = 0; k < 2; ++k) {
        int q = tid + k * 256;
        int row = q >> 2, sp = q & 3;
        int slot = sp ^ ((row >> 1) & 3);
        aOff[k] = (((row >> 6) * WP) + (row & 63)) * CI + slot * 8;
        bOff[k] = row * CI + slot * 8;
    }
    // fragment LDS offsets (elems): want (row, kslot g): s' = g ^ ((row>>1)&3)
    int lane = tid & 63, wid = tid >> 6;
    int wy = wid & 1, wx = wid >> 1;
    int g = lane >> 4, r16 = lane & 15;
    int fA[4], fB[4];
    #pragma unroll
    for (int m = 0; m < 4; ++m) {
        int ra = wy * 64 + m * 16 + r16;
        fA[m] = ra * BK + (g ^ ((ra >> 1) & 3)) * 8;
        int rb = wx * 64 + m * 16 + r16;
        fB[m] = rb * BK + (g ^ ((rb >> 1) & 3)) * 8;
    }

    f32x4 acc[4][4] = {};

    #pragma unroll 1
    for (int kh = 0; kh < 3; ++kh) {
        #pragma unroll 1
        for (int kw = 0; kw < 3; ++kw) {
            int tap = kh * 3 + kw;
            const unsigned short* aBase = xq + ((size_t)(n * HP + h0 + kh) * WP + kw) * CI;
            const unsigned short* bBase = wsum + ((size_t)tap * OC + oc0) * CI;
            #pragma unroll 1
            for (int c0 = 0; c0 < CI; c0 += BK) {
                __syncthreads();   // previous step's LDS readers done
                #pragma unroll
                for (int k = 0; k < 2; ++k) {
                    int q = tid + k * 256;
                    __builtin_amdgcn_global_load_lds(
                        (const __attribute__((address_space(1))) void*)(aBase + aOff[k] + c0),
                        (__attribute__((address_space(3))) void*)(&lA[q * 8]), 16, 0, 0);
                    __builtin_amdgcn_global_load_lds(
                        (const __attribute__((address_space(1))) void*)(bBase + bOff[k] + c0),
                        (__attribute__((address_space(3))) void*)(&lB[q * 8]), 16, 0, 0);
                }
                __syncthreads();   // drains vmcnt before barrier
                s16x8 af[4], bf[4];
                #pragma unroll
                for (int m = 0; m < 4; ++m) af[m] = *(const s16x8*)&lA[fA[m]];
                #pragma unroll
                for (int m = 0; m < 4; ++m) bf[m] = *(const s16x8*)&lB[fB[m]];
                #pragma unroll
                for (int m = 0; m < 4; ++m)
                    #pragma unroll
                    for (int nn = 0; nn < 4; ++nn)
                        acc[m][nn] = __builtin_amdgcn_mfma_f32_16x16x32_bf16(
                            af[m], bf[nn], acc[m][nn], 0, 0, 0);
            }
        }
    }

    // epilogue: C/D 16x16: col=lane&15 (oc), row=(lane>>4)*4+reg (pixel)
    int hw0 = pb & 4095;
    #pragma unroll
    for (int m = 0; m < 4; ++m) {
        int pl = wy * 64 + m * 16 + g * 4;
        #pragma unroll
        for (int nn = 0; nn < 4; ++nn) {
            int oc = oc0 + wx * 64 + nn * 16 + r16;
            float4 v;
            v.x = acc[m][nn][0]; v.y = acc[m][nn][1];
            v.z = acc[m][nn][2]; v.w = acc[m][nn][3];
            *(float4*)(out + ((size_t)(n * OC + oc) << 12) + hw0 + pl) = v;
        }
    }
}

extern "C" void kernel_launch(void* const* d_in, const int* in_sizes, int n_in,
                              void* d_out, int out_size, void* d_ws, size_t ws_size,
                              hipStream_t stream) {
    (void)in_sizes; (void)n_in; (void)out_size; (void)ws_size;
    const float* x   = (const float*)d_in[0];
    const float* wts = (const float*)d_in[1];
    float* out = (float*)d_out;
    char* wsb = (char*)d_ws;
    float* part            = (float*)wsb;                 // 320 floats
    float* scales          = (float*)(wsb + 2048);        // 5 floats
    unsigned short* wsum   = (unsigned short*)(wsb + 4096);          // 9*256*256 bf16 = 1.125 MiB
    unsigned short* xq     = (unsigned short*)(wsb + (size_t)(2u << 20)); // 8*66*66*256 bf16 ~ 17 MiB

    hipLaunchKernelGGL(k_abs_partial, dim3(NBASES * 64), dim3(256), 0, stream, wts, part);
    hipLaunchKernelGGL(k_scales,      dim3(1),           dim3(320), 0, stream, part, scales);
    hipLaunchKernelGGL(k_wsum,        dim3(OC),          dim3(256), 0, stream, wts, scales, wsum);
    hipLaunchKernelGGL(k_quant,       dim3(NB * HH),     dim3(256), 0, stream, x, xq);
    hipLaunchKernelGGL(k_conv, dim3((NB * HH * WW / BM) * (OC / BN)), dim3(256), 0, stream,
                       xq, wsum, out);
}